// Round 15
// baseline (487.824 us; speedup 1.0000x reference)
//
#include <hip/hip_runtime.h>
#include <math.h>

#define TID ((int)threadIdx.x)
#define LANE (TID & 63)

// ---------- constants ----------
#define NB 1024
#define NSEG 14
#define INP 504
#define ED 128
#define HD 256
#define ROWS (NB * NSEG)          // rows per ensemble = 14336
#define NROWS (4 * ROWS)          // 57344

typedef __attribute__((ext_vector_type(8))) short  bf16x8;
typedef __attribute__((ext_vector_type(8))) unsigned short u16x8;
typedef __attribute__((ext_vector_type(4))) float  f32x4;

__device__ __forceinline__ unsigned short f2bf(float f) {   // RNE f32->bf16
    unsigned int u = __float_as_uint(f);
    unsigned int r = (u + 0x7FFFu + ((u >> 16) & 1u)) >> 16;
    return (unsigned short)r;
}

// =======================================================================
// wave helpers (R14-proven)
// =======================================================================
__device__ __forceinline__ float wsum1(float v) {
    #pragma unroll
    for (int off = 32; off; off >>= 1) v += __shfl_xor(v, off, 64);
    return v;
}

__device__ __forceinline__ float rdlane(float v, int l) {
    return __int_as_float(__builtin_amdgcn_readlane(__float_as_int(v), l));
}

template<int E>
__device__ __forceinline__ float wssx(const float* v) {  // sum_{j>=1} v_j^2
    float s = (LANE == 0) ? 0.f : v[0] * v[0];
    #pragma unroll
    for (int t = 1; t < E; ++t) s += v[t] * v[t];
    return wsum1(s);
}

template<int E>
__device__ __forceinline__ float wlinE(const float* x, const float* y) {  // Minkowski
    float s = (LANE == 0) ? -x[0] * y[0] : x[0] * y[0];
    #pragma unroll
    for (int t = 1; t < E; ++t) s += x[t] * y[t];
    return wsum1(s);
}

template<int E>
__device__ __forceinline__ float w_exp0(float* v) {      // projx(safe_expmap0(v))
    float ss = wssx<E>(v);
    float n  = sqrtf(fmaxf(ss, 1e-12f));
    float th = fminf(n, 10.0f);
    float sc = sinhf(th) / n;
    #pragma unroll
    for (int t = 0; t < E; ++t) v[t] *= sc;
    float ss2 = sc * sc * ss;
    if (LANE == 0) v[0] = sqrtf(1.0f + ss2);
    return ss2;
}

template<int E>
__device__ __forceinline__ void w_log0k(float* v, float ss2) {  // logmap0, known ss2
    float x0 = sqrtf(1.0f + ss2);
    float d  = acoshf(fmaxf(x0, 1.0f + 1e-7f));
    float sc = d / sqrtf(fmaxf(ss2, 1e-12f));
    #pragma unroll
    for (int t = 0; t < E; ++t) v[t] *= sc;
    if (LANE == 0) v[0] = 0.f;
}

template<int E>
__device__ __forceinline__ void w_log0(float* v) {
    float ss = wssx<E>(v);
    float x0 = __shfl(v[0], 0, 64);
    float d  = acoshf(fmaxf(x0, 1.0f + 1e-7f));
    float sc = d / sqrtf(fmaxf(ss, 1e-12f));
    #pragma unroll
    for (int t = 0; t < E; ++t) v[t] *= sc;
    if (LANE == 0) v[0] = 0.f;
}

// scalar mid-chain: exp0,log0,exp0,log0 net scale (ss excludes comp-0)
__device__ __forceinline__ float chain_mid(float ss) {
    float n   = sqrtf(fmaxf(ss, 1e-12f));
    float th  = fminf(n, 10.0f);
    float sc1 = sinhf(th) / n;
    float ss2 = sc1 * sc1 * ss;
    float x0  = sqrtf(1.0f + ss2);
    float d   = acoshf(fmaxf(x0, 1.0f + 1e-7f));
    float sc2 = d / sqrtf(fmaxf(ss2, 1e-12f));
    float ss3 = sc2 * sc2 * ss2;
    float n2  = sqrtf(fmaxf(ss3, 1e-12f));
    float th2 = fminf(n2, 10.0f);
    float sc3 = sinhf(th2) / n2;
    float ss4 = sc3 * sc3 * ss3;
    float x02 = sqrtf(1.0f + ss4);
    float d2  = acoshf(fmaxf(x02, 1.0f + 1e-7f));
    float sc4 = d2 / sqrtf(fmaxf(ss4, 1e-12f));
    return sc1 * sc2 * sc3 * sc4;
}

// =======================================================================
// K_prep_stats (R14-proven)
// =======================================================================
__global__ __launch_bounds__(256) void k_prep_stats(
    const float* __restrict__ i0, const float* __restrict__ i1,
    const float* __restrict__ i2, const float* __restrict__ i3,
    const float* __restrict__ esc, float* __restrict__ rowAB)
{
    int row = blockIdx.x * 4 + (TID >> 6);
    int e = row / ROWS;
    int r = row - e * ROWS;
    const float* src = (e == 0 ? i0 : e == 1 ? i1 : e == 2 ? i2 : i3) + (size_t)r * INP;

    float x[8];
    #pragma unroll
    for (int t = 0; t < 7; ++t) x[t] = src[64 * t + LANE];
    x[7] = (LANE < 56) ? src[448 + LANE] : 0.f;

    float s = 0.f;
    #pragma unroll
    for (int t = 0; t < 8; ++t) s += x[t];
    s = wsum1(s);
    float mu = s * (1.0f / 504.0f);
    #pragma unroll
    for (int t = 0; t < 7; ++t) x[t] -= mu;
    x[7] = (LANE < 56) ? x[7] - mu : 0.f;

    float ss = 0.f;
    #pragma unroll
    for (int t = 0; t < 8; ++t) ss += x[t] * x[t];
    ss = wsum1(ss);
    float sd  = sqrtf(ss * (1.0f / 503.0f)) + 1e-6f;
    float inv = tanhf(esc[0]) / sd;

    float x0c = __shfl(x[0], 0, 64);
    float e2 = (ss - x0c * x0c) * inv * inv;
    float n  = sqrtf(fmaxf(e2, 1e-12f));
    float th = fminf(n, 10.0f);
    float sc1 = sinhf(th) / n;
    float e3 = sc1 * sc1 * e2;
    float h0 = sqrtf(1.0f + e3);
    float d  = acoshf(fmaxf(h0, 1.0f + 1e-7f));
    float sc2 = d / sqrtf(fmaxf(e3, 1e-12f));
    float A = inv * sc1 * sc2;
    float B = -mu * A;
    if (LANE == 0) {
        rowAB[2 * row]     = A;
        rowAB[2 * row + 1] = B;
    }
}

// =======================================================================
// W pre-transpose + bf16 convert
// =======================================================================
template<int K, int KP>
__global__ __launch_bounds__(256) void k_wtrans(
    const float* __restrict__ W, unsigned short* __restrict__ out)
{
    int g = blockIdx.x * 256 + TID;
    int k = g % KP;
    int c = (g / KP) % 128;
    int e = g / (KP * 128);
    float v = (k < K) ? W[(size_t)e * K * 128 + (size_t)k * 128 + c] : 0.f;
    out[g] = f2bf(v);
}

__global__ __launch_bounds__(256) void k_wtrans2(
    const float* __restrict__ W1, unsigned short* __restrict__ o1,
    const float* __restrict__ W2, unsigned short* __restrict__ o2)
{
    const int NPER = 4 * 128 * 128;
    int g = blockIdx.x * 256 + TID;
    const float* W = (g < NPER) ? W1 : W2;
    unsigned short* o = (g < NPER) ? o1 : o2;
    int gl = (g < NPER) ? g : g - NPER;
    int k = gl % 128;
    int c = (gl / 128) % 128;
    int e = gl / (128 * 128);
    o[gl] = f2bf(W[(size_t)e * 128 * 128 + (size_t)k * 128 + c]);
}

// =======================================================================
// bf16 MFMA GEMM; MID=true fuses the k_mid row chain into the epilogue.
// acc layout (R11-verified): row = wr + rt*16 + (l>>4)*4 + j,
//                            col = wc + ct*16 + (l&15).
// Row ss reduction: 4-step shfl_xor over low-4 lane bits (cols within
// wave), then cross-wave combine via ssbuf LDS (row split w <-> w^2).
// =======================================================================
template<int K, int KP, bool PREP, bool MID>
__global__ __launch_bounds__(256) void k_gemm_bf(
    const float* __restrict__ U,
    const float* __restrict__ i0, const float* __restrict__ i1,
    const float* __restrict__ i2, const float* __restrict__ i3,
    const float* __restrict__ rowAB,
    const unsigned short* __restrict__ WtTg, const float* __restrict__ bg,
    float* __restrict__ Y)
{
    __shared__ unsigned short UtL[64][72];
    __shared__ unsigned short WtL[128][72];
    __shared__ float sA[64], sB[64];
    __shared__ float ssbuf[4][32];

    int row0 = blockIdx.x * 64;
    int e = row0 / ROWS;
    const unsigned short* Wp = WtTg + (size_t)e * 128 * KP;

    const float* srcp;
    int rbase;
    if (PREP) {
        srcp = (e == 0 ? i0 : e == 1 ? i1 : e == 2 ? i2 : i3);
        rbase = row0 - e * ROWS;
        if (TID < 64) {
            sA[TID] = rowAB[2 * (row0 + TID)];
            sB[TID] = rowAB[2 * (row0 + TID) + 1];
        }
    } else {
        srcp = U;
        rbase = row0;
    }

    int w  = TID >> 6;
    int l  = LANE;
    int wr = (w & 1) * 32;
    int wc = (w >> 1) * 64;
    int fr = l & 15;
    int g  = l >> 4;                 // lane group 0..3
    int koff = g * 8;

    f32x4 acc[2][4];
    #pragma unroll
    for (int rt = 0; rt < 2; ++rt)
        #pragma unroll
        for (int ct = 0; ct < 4; ++ct)
            acc[rt][ct] = (f32x4){0.f, 0.f, 0.f, 0.f};

    for (int k0 = 0; k0 < KP; k0 += 64) {
        __syncthreads();
        #pragma unroll
        for (int t = 0; t < 2; ++t) {
            int idx = TID + t * 256;
            int row = idx >> 3;
            int kq  = idx & 7;
            int gk  = k0 + kq * 8;
            u16x8 o;
            if (gk < K) {
                const float* sp = &srcp[(size_t)(rbase + row) * K + gk];
                float4 v0 = *(const float4*)sp;
                float4 v1 = *(const float4*)(sp + 4);
                if (PREP) {
                    float a = sA[row], bb = sB[row];
                    v0.x = v0.x * a + bb; v0.y = v0.y * a + bb;
                    v0.z = v0.z * a + bb; v0.w = v0.w * a + bb;
                    v1.x = v1.x * a + bb; v1.y = v1.y * a + bb;
                    v1.z = v1.z * a + bb; v1.w = v1.w * a + bb;
                    if (gk == 0) v0.x = 0.f;
                }
                o[0] = f2bf(v0.x); o[1] = f2bf(v0.y); o[2] = f2bf(v0.z); o[3] = f2bf(v0.w);
                o[4] = f2bf(v1.x); o[5] = f2bf(v1.y); o[6] = f2bf(v1.z); o[7] = f2bf(v1.w);
            } else {
                o = (u16x8){0,0,0,0,0,0,0,0};
            }
            *(u16x8*)&UtL[row][kq * 8] = o;
        }
        #pragma unroll
        for (int t = 0; t < 4; ++t) {
            int idx = TID + t * 256;
            int c  = idx >> 3;
            int kq = idx & 7;
            u16x8 wv = *(const u16x8*)&Wp[(size_t)c * KP + k0 + kq * 8];
            *(u16x8*)&WtL[c][kq * 8] = wv;
        }
        __syncthreads();

        #pragma unroll
        for (int ks = 0; ks < 2; ++ks) {
            bf16x8 af[2];
            #pragma unroll
            for (int rt = 0; rt < 2; ++rt)
                af[rt] = *(const bf16x8*)&UtL[wr + rt * 16 + fr][ks * 32 + koff];
            #pragma unroll
            for (int ct = 0; ct < 4; ++ct) {
                bf16x8 bf = *(const bf16x8*)&WtL[wc + ct * 16 + fr][ks * 32 + koff];
                acc[0][ct] = __builtin_amdgcn_mfma_f32_16x16x32_bf16(af[0], bf, acc[0][ct], 0, 0, 0);
                acc[1][ct] = __builtin_amdgcn_mfma_f32_16x16x32_bf16(af[1], bf, acc[1][ct], 0, 0, 0);
            }
        }
    }

    // ---- epilogue: bias, then (MID) per-row scalar chain, then store
    #pragma unroll
    for (int ct = 0; ct < 4; ++ct) {
        float bv = bg[e * 128 + wc + ct * 16 + fr];
        #pragma unroll
        for (int rt = 0; rt < 2; ++rt)
            #pragma unroll
            for (int j = 0; j < 4; ++j)
                acc[rt][ct][j] += bv;
    }

    float S[8];
    if (MID) {
        bool skip0 = (wc == 0) && (fr == 0);   // this lane's ct==0 col is global col 0
        float pss[8];
        #pragma unroll
        for (int rt = 0; rt < 2; ++rt)
            #pragma unroll
            for (int j = 0; j < 4; ++j) {
                float a0 = acc[rt][0][j];
                float q = acc[rt][1][j] * acc[rt][1][j]
                        + acc[rt][2][j] * acc[rt][2][j]
                        + acc[rt][3][j] * acc[rt][3][j];
                pss[rt * 4 + j] = q + (skip0 ? 0.f : a0 * a0);
            }
        #pragma unroll
        for (int off = 1; off < 16; off <<= 1) {
            #pragma unroll
            for (int i = 0; i < 8; ++i) pss[i] += __shfl_xor(pss[i], off, 64);
        }
        // lane fr==0 of each group writes its 8 row-partials
        if (fr == 0) {
            #pragma unroll
            for (int rt = 0; rt < 2; ++rt)
                #pragma unroll
                for (int j = 0; j < 4; ++j)
                    ssbuf[w][rt * 16 + g * 4 + j] = pss[rt * 4 + j];
        }
        __syncthreads();
        #pragma unroll
        for (int rt = 0; rt < 2; ++rt)
            #pragma unroll
            for (int j = 0; j < 4; ++j) {
                int ridx = rt * 16 + g * 4 + j;
                float sst = ssbuf[w][ridx] + ssbuf[w ^ 2][ridx];
                S[rt * 4 + j] = chain_mid(sst);
            }
    }

    #pragma unroll
    for (int rt = 0; rt < 2; ++rt) {
        #pragma unroll
        for (int ct = 0; ct < 4; ++ct) {
            int col = wc + ct * 16 + fr;
            #pragma unroll
            for (int j = 0; j < 4; ++j) {
                int row = row0 + wr + rt * 16 + g * 4 + j;
                float o = acc[rt][ct][j];
                if (MID) {
                    o *= S[rt * 4 + j];
                    if (col == 0) o = 0.f;
                }
                Y[(size_t)row * 128 + col] = o;
            }
        }
    }
}

// =======================================================================
// frechet mean; FE=true fuses the final per-row exp0 (R14-proven)
// =======================================================================
template<int NPTS, bool FE>
__global__ __launch_bounds__(256) void k_frechet_w(
    const float* __restrict__ src, size_t blk_stride, size_t p_stride,
    float* __restrict__ dst)
{
    int prob = blockIdx.x * 4 + (TID >> 6);
    const float* base = src + (size_t)prob * blk_stride;
    float pa[NPTS], pb[NPTS];
    #pragma unroll
    for (int p = 0; p < NPTS; ++p) {
        pa[p] = base[(size_t)p * p_stride + LANE];
        pb[p] = base[(size_t)p * p_stride + 64 + LANE];
    }

    if (FE) {
        float q[NPTS];
        #pragma unroll
        for (int p = 0; p < NPTS; ++p)
            q[p] = ((LANE == 0) ? 0.f : pa[p] * pa[p]) + pb[p] * pb[p];
        #pragma unroll
        for (int off = 32; off; off >>= 1) {
            #pragma unroll
            for (int p = 0; p < NPTS; ++p) q[p] += __shfl_xor(q[p], off, 64);
        }
        float ssp = 0.f;
        #pragma unroll
        for (int p = 0; p < NPTS; ++p) if (LANE == p) ssp = q[p];
        float nn  = sqrtf(fmaxf(ssp, 1e-12f));
        float th  = fminf(nn, 10.0f);
        float scp = sinhf(th) / nn;
        float c0p = sqrtf(1.0f + scp * scp * ssp);
        #pragma unroll
        for (int p = 0; p < NPTS; ++p) {
            float sc = rdlane(scp, p);
            float c0 = rdlane(c0p, p);
            pa[p] = (LANE == 0) ? c0 : pa[p] * sc;
            pb[p] *= sc;
        }
    }

    float xp = 1.0f;
    #pragma unroll
    for (int p = 0; p < NPTS; ++p) {
        float x0 = __shfl(pa[p], 0, 64);
        if (LANE == p) xp = x0;
    }
    {
        float bcl = fmaxf(xp, 1.0f + 1e-7f);
        float sq  = sqrtf(fmaxf(bcl * bcl - 1.0f, 1e-12f));
        float dd  = acoshf(bcl);
        xp = dd / sq;
    }
    float ma = 0.f, mb = 0.f;
    #pragma unroll
    for (int p = 0; p < NPTS; ++p) {
        float cp = rdlane(xp, p);
        ma = fmaf(pa[p], cp, ma);
        mb = fmaf(pb[p], cp, mb);
    }
    if (LANE == 0) ma = 0.f;
    ma *= (1.0f / NPTS); mb *= (1.0f / NPTS);
    float cur[2] = { ma, mb };
    w_exp0<2>(cur);
    float ca = cur[0], cb = cur[1];

    for (int it = 0; it < 10; ++it) {
        float part[NPTS];
        #pragma unroll
        for (int p = 0; p < NPTS; ++p)
            part[p] = fmaf(cb, pb[p], (LANE == 0) ? -ca * pa[p] : ca * pa[p]);
        #pragma unroll
        for (int off = 32; off; off >>= 1) {
            #pragma unroll
            for (int p = 0; p < NPTS; ++p) part[p] += __shfl_xor(part[p], off, 64);
        }
        float lp = 0.f;
        #pragma unroll
        for (int p = 0; p < NPTS; ++p) if (LANE == p) lp = part[p];
        float bb  = fmaxf(-lp, 1.0f + 1e-7f);
        float squ = sqrtf(fmaxf(bb * bb - 1.0f, 1e-12f));
        float ccv = acoshf(bb) / squ;
        float gg  = (LANE < NPTS) ? ccv * bb : 0.f;
        float gv  = wsum1(gg);
        float va = 0.f, vb = 0.f;
        #pragma unroll
        for (int p = 0; p < NPTS; ++p) {
            float cp = rdlane(ccv, p);
            va = fmaf(pa[p], cp, va);
            vb = fmaf(pb[p], cp, vb);
        }
        const float sscale = 0.5f / NPTS;
        va = (va - gv * ca) * sscale;
        vb = (vb - gv * cb) * sscale;
        float lin = wsum1(((LANE == 0) ? -va * va : va * va) + vb * vb);
        float n   = sqrtf(fmaxf(lin, 1e-12f));
        float th  = fminf(n, 10.0f);
        float ch  = coshf(th), shn = sinhf(th) / n;
        float ya = ch * ca + shn * va;
        float yb = ch * cb + shn * vb;
        float ss2 = wsum1(((LANE == 0) ? 0.f : ya * ya) + yb * yb);
        ca = (LANE == 0) ? sqrtf(1.0f + ss2) : ya;
        cb = yb;
    }
    dst[(size_t)prob * 128 + LANE] = ca;
    dst[(size_t)prob * 128 + 64 + LANE] = cb;
}

// =======================================================================
// fused decode v4 (R14-proven verbatim)
// =======================================================================
__global__ __launch_bounds__(512) void k_decode_all(
    const float* __restrict__ comb,
    const float* __restrict__ dW0, const float* __restrict__ db0,
    const float* __restrict__ dW1, const float* __restrict__ db1,
    const float* __restrict__ dW2, const float* __restrict__ db2,
    const float* __restrict__ step_p, const float* __restrict__ alpha_p,
    const float* __restrict__ cW0, const float* __restrict__ cb0,
    const float* __restrict__ lng, const float* __restrict__ lnb,
    const float* __restrict__ cW1, const float* __restrict__ cb1,
    float* __restrict__ out)
{
    __shared__ float uT[2][256];
    __shared__ float Bbuf[2][256];
    __shared__ float part[1024];
    int w = TID >> 6;
    int row0 = blockIdx.x * 2;

    float zc0 = 1.f, zc1 = 0.f, x0 = 1.f, x1 = 0.f;
    if (w < 2) {
        size_t rb = (size_t)(row0 + w) * ED;
        zc0 = comb[rb + LANE]; zc1 = comb[rb + 64 + LANE];
        x0 = zc0; x1 = zc1;
    }
    float stp = 1.0f / (1.0f + expf(-step_p[0]));
    float aa  = 1.0f / (1.0f + expf(-alpha_p[0]));

    for (int s = 0; s < 4; ++s) {
        // ---- phase 1 (waves 0-1)
        if (w < 2) {
            float xx[2] = { x0, x1 };
            float zz[2] = { zc0, zc1 };
            float lin  = wlinE<2>(xx, zz);
            float beta = fmaxf(-lin, 1.0f + 1e-7f);
            float un   = sqrtf(fmaxf(beta * beta - 1.0f, 1e-12f));
            float sc   = acoshf(beta) / un;
            float v[2] = { sc * (zz[0] - beta * xx[0]), sc * (zz[1] - beta * xx[1]) };
            float ss2 = w_exp0<2>(v);
            w_log0k<2>(v, ss2);
            uT[w][LANE] = v[0]; uT[w][64 + LANE] = v[1];
        }
        __syncthreads();

        // ---- phase 2: y1 = u1 @ dW0 + db0  (128 -> 256), K-split 2
        {
            int kh = TID >> 8;
            int col = TID & 255;
            int k0 = kh * 64;
            float a0 = 0.f, a1 = 0.f;
            #pragma unroll 8
            for (int i = 0; i < 64; ++i) {
                float u0 = uT[0][k0 + i], u1 = uT[1][k0 + i];
                float wv = dW0[(size_t)(k0 + i) * HD + col];
                a0 = fmaf(u0, wv, a0); a1 = fmaf(u1, wv, a1);
            }
            if (kh == 1) { part[col] = a0; part[256 + col] = a1; }
            __syncthreads();
            if (kh == 0) {
                float b = db0[col];
                Bbuf[0][col] = a0 + part[col] + b;
                Bbuf[1][col] = a1 + part[256 + col] + b;
            }
        }
        __syncthreads();

        // ---- phase 3 (waves 0-1): u2 = mid-chain(y1)
        if (w < 2) {
            float y[4];
            #pragma unroll
            for (int t = 0; t < 4; ++t) y[t] = Bbuf[w][t * 64 + LANE];
            float ss2 = w_exp0<4>(y);
            w_log0k<4>(y, ss2);
            ss2 = w_exp0<4>(y);
            w_log0k<4>(y, ss2);
            #pragma unroll
            for (int t = 0; t < 4; ++t) uT[w][t * 64 + LANE] = y[t];
        }
        __syncthreads();

        // ---- phase 4: y2 = u2 @ dW1 + db1  (256 -> 256), K-split 2
        {
            int kh = TID >> 8;
            int col = TID & 255;
            int k0 = kh * 128;
            float a0 = 0.f, a1 = 0.f;
            #pragma unroll 8
            for (int i = 0; i < 128; ++i) {
                float u0 = uT[0][k0 + i], u1 = uT[1][k0 + i];
                float wv = dW1[(size_t)(k0 + i) * HD + col];
                a0 = fmaf(u0, wv, a0); a1 = fmaf(u1, wv, a1);
            }
            if (kh == 1) { part[col] = a0; part[256 + col] = a1; }
            __syncthreads();
            if (kh == 0) {
                float b = db1[col];
                Bbuf[0][col] = a0 + part[col] + b;
                Bbuf[1][col] = a1 + part[256 + col] + b;
            }
        }
        __syncthreads();

        // ---- phase 5 (waves 0-1): u3 = mid-chain(y2)
        if (w < 2) {
            float y[4];
            #pragma unroll
            for (int t = 0; t < 4; ++t) y[t] = Bbuf[w][t * 64 + LANE];
            float ss2 = w_exp0<4>(y);
            w_log0k<4>(y, ss2);
            ss2 = w_exp0<4>(y);
            w_log0k<4>(y, ss2);
            #pragma unroll
            for (int t = 0; t < 4; ++t) uT[w][t * 64 + LANE] = y[t];
        }
        __syncthreads();

        // ---- phase 6: y3 = u3 @ dW2 + db2  (256 -> 128), K-split 4
        {
            int kq = TID >> 7;
            int col = TID & 127;
            int k0 = kq * 64;
            float a0 = 0.f, a1 = 0.f;
            #pragma unroll 8
            for (int i = 0; i < 64; ++i) {
                float u0 = uT[0][k0 + i], u1 = uT[1][k0 + i];
                float wv = dW2[(size_t)(k0 + i) * ED + col];
                a0 = fmaf(u0, wv, a0); a1 = fmaf(u1, wv, a1);
            }
            if (kq > 0) {
                part[(kq - 1) * 256 + col] = a0;
                part[(kq - 1) * 256 + 128 + col] = a1;
            }
            __syncthreads();
            if (kq == 0) {
                float b = db2[col];
                float s0 = a0, s1 = a1;
                #pragma unroll
                for (int q = 0; q < 3; ++q) {
                    s0 += part[q * 256 + col];
                    s1 += part[q * 256 + 128 + col];
                }
                Bbuf[0][col] = s0 + b;
                Bbuf[1][col] = s1 + b;
            }
        }
        __syncthreads();

        // ---- phase 7 (waves 0-1): vtr; zstep; rotate; u4
        if (w < 2) {
            float y[2] = { Bbuf[w][LANE], Bbuf[w][64 + LANE] };
            float ss2v = w_exp0<2>(y);
            w_log0k<2>(y, ss2v);

            float z[2] = { zc0, zc1 };
            float u[2] = { stp * y[0], stp * y[1] };
            float lin1 = wlinE<2>(u, u);
            float n1   = sqrtf(fmaxf(lin1, 1e-12f));
            float th1  = fminf(n1, 10.0f);
            float ch1  = coshf(th1), sh1 = sinhf(th1) / n1;
            float zu[2] = { ch1 * z[0] + sh1 * u[0], ch1 * z[1] + sh1 * u[1] };
            float s2 = wsum1(((LANE == 0) ? 0.f : zu[0] * zu[0]) + zu[1] * zu[1]);
            if (LANE == 0) zu[0] = sqrtf(1.0f + s2);
            float lin2 = wlinE<2>(z, zu);
            float beta = fmaxf(-lin2, 1.0f + 1e-7f);
            float un   = sqrtf(fmaxf(beta * beta - 1.0f, 1e-12f));
            float dd   = acoshf(beta);
            float sc   = dd / un;
            float g0 = (1.0f - aa) * sc * (zu[0] - beta * z[0]);
            float g1 = (1.0f - aa) * sc * (zu[1] - beta * z[1]);
            float n3  = sqrtf(fmaxf((1.0f - aa) * (1.0f - aa) * dd * dd, 1e-12f));
            float th3 = fminf(n3, 10.0f);
            float ch3 = coshf(th3), sh3 = sinhf(th3) / n3;
            float y0 = ch3 * z[0] + sh3 * g0;
            float y1 = ch3 * z[1] + sh3 * g1;
            float s3 = wsum1(((LANE == 0) ? 0.f : y0 * y0) + y1 * y1);
            if (LANE == 0) y0 = sqrtf(1.0f + s3);
            x0 = zc0; x1 = zc1;
            zc0 = y0; zc1 = y1;
            float x0b = sqrtf(1.0f + s3);
            float dd2 = acoshf(fmaxf(x0b, 1.0f + 1e-7f));
            float sc4 = dd2 / sqrtf(fmaxf(s3, 1e-12f));
            uT[w][LANE]      = (LANE == 0) ? 0.f : y0 * sc4;
            uT[w][64 + LANE] = y1 * sc4;
        }
        __syncthreads();

        // ---- phase 8: t = u4 @ cW0 + cb0  (128 -> 256), K-split 2
        {
            int kh = TID >> 8;
            int col = TID & 255;
            int k0 = kh * 64;
            float a0 = 0.f, a1 = 0.f;
            #pragma unroll 8
            for (int i = 0; i < 64; ++i) {
                float u0 = uT[0][k0 + i], u1 = uT[1][k0 + i];
                float wv = cW0[(size_t)(k0 + i) * HD + col];
                a0 = fmaf(u0, wv, a0); a1 = fmaf(u1, wv, a1);
            }
            if (kh == 1) { part[col] = a0; part[256 + col] = a1; }
            __syncthreads();
            if (kh == 0) {
                float b = cb0[col];
                Bbuf[0][col] = a0 + part[col] + b;
                Bbuf[1][col] = a1 + part[256 + col] + b;
            }
        }
        __syncthreads();

        // ---- phase 9 (waves 0-1): LayerNorm + exact GELU
        if (w < 2) {
            float tv[4];
            #pragma unroll
            for (int t = 0; t < 4; ++t) tv[t] = Bbuf[w][t * 64 + LANE];
            float m = wsum1(tv[0] + tv[1] + tv[2] + tv[3]) * (1.0f / 256.0f);
            float c[4]; float vs = 0.f;
            #pragma unroll
            for (int t = 0; t < 4; ++t) { c[t] = tv[t] - m; vs += c[t] * c[t]; }
            float var = wsum1(vs) * (1.0f / 256.0f);
            float rstd = 1.0f / sqrtf(var + 1e-5f);
            #pragma unroll
            for (int t = 0; t < 4; ++t) {
                float g = lng[t * 64 + LANE], bb = lnb[t * 64 + LANE];
                float x = c[t] * rstd * g + bb;
                uT[w][t * 64 + LANE] = 0.5f * x * (1.0f + erff(x * 0.70710678118654752f));
            }
        }
        __syncthreads();

        // ---- phase 10: out = gelu(t) @ cW1 + cb1  (256 -> 504), K-split 2
        {
            int kh = TID >> 8;
            int c  = TID & 255;
            bool hi = (c < 248);
            int k0 = kh * 128;
            float a00 = 0.f, a01 = 0.f, a10 = 0.f, a11 = 0.f;
            #pragma unroll 8
            for (int i = 0; i < 128; ++i) {
                float u0 = uT[0][k0 + i], u1 = uT[1][k0 + i];
                float wA = cW1[(size_t)(k0 + i) * 504 + c];
                float wB = hi ? cW1[(size_t)(k0 + i) * 504 + c + 256] : 0.f;
                a00 = fmaf(u0, wA, a00); a01 = fmaf(u0, wB, a01);
                a10 = fmaf(u1, wA, a10); a11 = fmaf(u1, wB, a11);
            }
            if (kh == 1) {
                part[c] = a00; part[256 + c] = a01;
                part[512 + c] = a10; part[768 + c] = a11;
            }
            __syncthreads();
            if (kh == 0) {
                float bA = cb1[c];
                float bB = hi ? cb1[c + 256] : 0.f;
                size_t ob0 = (size_t)(row0 + 0) * 2016 + (size_t)s * 504;
                size_t ob1 = (size_t)(row0 + 1) * 2016 + (size_t)s * 504;
                out[ob0 + c] = a00 + part[c] + bA;
                out[ob1 + c] = a10 + part[512 + c] + bA;
                if (hi) {
                    out[ob0 + c + 256] = a01 + part[256 + c] + bB;
                    out[ob1 + c + 256] = a11 + part[768 + c] + bB;
                }
            }
        }
        __syncthreads();
    }
}

// ---------- launch ----------
extern "C" void kernel_launch(void* const* d_in, const int* in_sizes, int n_in,
                              void* d_out, int out_size, void* d_ws, size_t ws_size,
                              hipStream_t stream) {
    const float* trend = (const float*)d_in[0];
    const float* scrs  = (const float*)d_in[1];
    const float* sfin  = (const float*)d_in[2];
    const float* resid = (const float*)d_in[3];
    const float* eW0 = (const float*)d_in[4];
    const float* eb0 = (const float*)d_in[5];
    const float* eW1 = (const float*)d_in[6];
    const float* eb1 = (const float*)d_in[7];
    const float* eW2 = (const float*)d_in[8];
    const float* eb2 = (const float*)d_in[9];
    const float* esc = (const float*)d_in[10];
    const float* dW0 = (const float*)d_in[12];
    const float* db0 = (const float*)d_in[13];
    const float* dW1 = (const float*)d_in[14];
    const float* db1 = (const float*)d_in[15];
    const float* dW2 = (const float*)d_in[16];
    const float* db2 = (const float*)d_in[17];
    const float* alpha_p = (const float*)d_in[18];
    const float* step_p  = (const float*)d_in[19];
    const float* cW0 = (const float*)d_in[20];
    const float* cb0 = (const float*)d_in[21];
    const float* lng = (const float*)d_in[22];
    const float* lnb = (const float*)d_in[23];
    const float* cW1 = (const float*)d_in[24];
    const float* cb1 = (const float*)d_in[25];
    float* outp = (float*)d_out;

    float* w = (float*)d_ws;
    float* Y      = w;                        // 7,340,032 f32
    float* pooled = Y + 7340032;              // 524,288
    float* comb   = pooled + 524288;          // 131,072
    float* rowAB  = comb + 131072;            // 114,688
    unsigned short* WtT0 = (unsigned short*)(rowAB + 114688);  // 4*128*512 u16
    unsigned short* WtT1 = WtT0 + 4 * 128 * 512;               // 4*128*128 u16
    unsigned short* WtT2 = WtT1 + 4 * 128 * 128;               // 4*128*128 u16

    // ---- weight pre-transpose + bf16 convert ----
    k_wtrans<504, 512><<<(4 * 128 * 512) / 256, 256, 0, stream>>>(eW0, WtT0);
    k_wtrans2<<<(2 * 4 * 128 * 128) / 256, 256, 0, stream>>>(eW1, WtT1, eW2, WtT2);

    // ---- encoder: bf16 MFMA GEMMs with fused mid-chain epilogues ----
    k_prep_stats<<<NROWS / 4, 256, 0, stream>>>(trend, scrs, sfin, resid, esc, rowAB);
    k_gemm_bf<504, 512, true,  true ><<<NROWS / 64, 256, 0, stream>>>(
        nullptr, trend, scrs, sfin, resid, rowAB, WtT0, eb0, Y);
    k_gemm_bf<128, 128, false, true ><<<NROWS / 64, 256, 0, stream>>>(
        Y, nullptr, nullptr, nullptr, nullptr, nullptr, WtT1, eb1, Y);
    k_gemm_bf<128, 128, false, false><<<NROWS / 64, 256, 0, stream>>>(
        Y, nullptr, nullptr, nullptr, nullptr, nullptr, WtT2, eb2, Y);

    // ---- frechet pooling (point-load applies exp0) ----
    k_frechet_w<NSEG, true><<<(4 * NB) / 4, 256, 0, stream>>>(
        Y, (size_t)NSEG * ED, (size_t)ED, pooled);
    k_frechet_w<4, false><<<NB / 4, 256, 0, stream>>>(
        pooled, (size_t)ED, (size_t)NB * ED, comb);

    // ---- decode (R14-proven) ----
    k_decode_all<<<NB / 2, 512, 0, stream>>>(
        comb, dW0, db0, dW1, db1, dW2, db2, step_p, alpha_p,
        cW0, cb0, lng, lnb, cW1, cb1, outp);
}

// Round 16
// 423.585 us; speedup vs baseline: 1.1517x; 1.1517x over previous
//
#include <hip/hip_runtime.h>
#include <math.h>

#define TID ((int)threadIdx.x)
#define LANE (TID & 63)

// ---------- constants ----------
#define NB 1024
#define NSEG 14
#define INP 504
#define ED 128
#define HD 256
#define ROWS (NB * NSEG)          // rows per ensemble = 14336
#define NROWS (4 * ROWS)          // 57344

typedef __attribute__((ext_vector_type(8))) short  bf16x8;
typedef __attribute__((ext_vector_type(8))) unsigned short u16x8;
typedef __attribute__((ext_vector_type(4))) float  f32x4;

__device__ __forceinline__ unsigned short f2bf(float f) {   // RNE f32->bf16
    unsigned int u = __float_as_uint(f);
    unsigned int r = (u + 0x7FFFu + ((u >> 16) & 1u)) >> 16;
    return (unsigned short)r;
}

// =======================================================================
// wave helpers (R14-proven)
// =======================================================================
__device__ __forceinline__ float wsum1(float v) {
    #pragma unroll
    for (int off = 32; off; off >>= 1) v += __shfl_xor(v, off, 64);
    return v;
}

__device__ __forceinline__ float rdlane(float v, int l) {
    return __int_as_float(__builtin_amdgcn_readlane(__float_as_int(v), l));
}

template<int E>
__device__ __forceinline__ float wssx(const float* v) {  // sum_{j>=1} v_j^2
    float s = (LANE == 0) ? 0.f : v[0] * v[0];
    #pragma unroll
    for (int t = 1; t < E; ++t) s += v[t] * v[t];
    return wsum1(s);
}

template<int E>
__device__ __forceinline__ float wlinE(const float* x, const float* y) {  // Minkowski
    float s = (LANE == 0) ? -x[0] * y[0] : x[0] * y[0];
    #pragma unroll
    for (int t = 1; t < E; ++t) s += x[t] * y[t];
    return wsum1(s);
}

template<int E>
__device__ __forceinline__ float w_exp0(float* v) {      // projx(safe_expmap0(v))
    float ss = wssx<E>(v);
    float n  = sqrtf(fmaxf(ss, 1e-12f));
    float th = fminf(n, 10.0f);
    float sc = sinhf(th) / n;
    #pragma unroll
    for (int t = 0; t < E; ++t) v[t] *= sc;
    float ss2 = sc * sc * ss;
    if (LANE == 0) v[0] = sqrtf(1.0f + ss2);
    return ss2;
}

template<int E>
__device__ __forceinline__ void w_log0k(float* v, float ss2) {  // logmap0, known ss2
    float x0 = sqrtf(1.0f + ss2);
    float d  = acoshf(fmaxf(x0, 1.0f + 1e-7f));
    float sc = d / sqrtf(fmaxf(ss2, 1e-12f));
    #pragma unroll
    for (int t = 0; t < E; ++t) v[t] *= sc;
    if (LANE == 0) v[0] = 0.f;
}

template<int E>
__device__ __forceinline__ void w_log0(float* v) {
    float ss = wssx<E>(v);
    float x0 = __shfl(v[0], 0, 64);
    float d  = acoshf(fmaxf(x0, 1.0f + 1e-7f));
    float sc = d / sqrtf(fmaxf(ss, 1e-12f));
    #pragma unroll
    for (int t = 0; t < E; ++t) v[t] *= sc;
    if (LANE == 0) v[0] = 0.f;
}

// =======================================================================
// K_prep_stats (R14-proven)
// =======================================================================
__global__ __launch_bounds__(256) void k_prep_stats(
    const float* __restrict__ i0, const float* __restrict__ i1,
    const float* __restrict__ i2, const float* __restrict__ i3,
    const float* __restrict__ esc, float* __restrict__ rowAB)
{
    int row = blockIdx.x * 4 + (TID >> 6);
    int e = row / ROWS;
    int r = row - e * ROWS;
    const float* src = (e == 0 ? i0 : e == 1 ? i1 : e == 2 ? i2 : i3) + (size_t)r * INP;

    float x[8];
    #pragma unroll
    for (int t = 0; t < 7; ++t) x[t] = src[64 * t + LANE];
    x[7] = (LANE < 56) ? src[448 + LANE] : 0.f;

    float s = 0.f;
    #pragma unroll
    for (int t = 0; t < 8; ++t) s += x[t];
    s = wsum1(s);
    float mu = s * (1.0f / 504.0f);
    #pragma unroll
    for (int t = 0; t < 7; ++t) x[t] -= mu;
    x[7] = (LANE < 56) ? x[7] - mu : 0.f;

    float ss = 0.f;
    #pragma unroll
    for (int t = 0; t < 8; ++t) ss += x[t] * x[t];
    ss = wsum1(ss);
    float sd  = sqrtf(ss * (1.0f / 503.0f)) + 1e-6f;
    float inv = tanhf(esc[0]) / sd;

    float x0c = __shfl(x[0], 0, 64);
    float e2 = (ss - x0c * x0c) * inv * inv;
    float n  = sqrtf(fmaxf(e2, 1e-12f));
    float th = fminf(n, 10.0f);
    float sc1 = sinhf(th) / n;
    float e3 = sc1 * sc1 * e2;
    float h0 = sqrtf(1.0f + e3);
    float d  = acoshf(fmaxf(h0, 1.0f + 1e-7f));
    float sc2 = d / sqrtf(fmaxf(e3, 1e-12f));
    float A = inv * sc1 * sc2;
    float B = -mu * A;
    if (LANE == 0) {
        rowAB[2 * row]     = A;
        rowAB[2 * row + 1] = B;
    }
}

// =======================================================================
// W pre-transpose + bf16 convert
// =======================================================================
template<int K, int KP>
__global__ __launch_bounds__(256) void k_wtrans(
    const float* __restrict__ W, unsigned short* __restrict__ out)
{
    int g = blockIdx.x * 256 + TID;
    int k = g % KP;
    int c = (g / KP) % 128;
    int e = g / (KP * 128);
    float v = (k < K) ? W[(size_t)e * K * 128 + (size_t)k * 128 + c] : 0.f;
    out[g] = f2bf(v);
}

__global__ __launch_bounds__(256) void k_wtrans2(
    const float* __restrict__ W1, unsigned short* __restrict__ o1,
    const float* __restrict__ W2, unsigned short* __restrict__ o2)
{
    const int NPER = 4 * 128 * 128;
    int g = blockIdx.x * 256 + TID;
    const float* W = (g < NPER) ? W1 : W2;
    unsigned short* o = (g < NPER) ? o1 : o2;
    int gl = (g < NPER) ? g : g - NPER;
    int k = gl % 128;
    int c = (gl / 128) % 128;
    int e = gl / (128 * 128);
    o[gl] = f2bf(W[(size_t)e * 128 * 128 + (size_t)k * 128 + c]);
}

// =======================================================================
// bf16 MFMA GEMM (encoder, R14-proven verbatim, plain bias epilogue)
// =======================================================================
template<int K, int KP, bool PREP>
__global__ __launch_bounds__(256) void k_gemm_bf(
    const float* __restrict__ U,
    const float* __restrict__ i0, const float* __restrict__ i1,
    const float* __restrict__ i2, const float* __restrict__ i3,
    const float* __restrict__ rowAB,
    const unsigned short* __restrict__ WtTg, const float* __restrict__ bg,
    float* __restrict__ Y)
{
    __shared__ unsigned short UtL[64][72];
    __shared__ unsigned short WtL[128][72];
    __shared__ float sA[64], sB[64];

    int row0 = blockIdx.x * 64;
    int e = row0 / ROWS;
    const unsigned short* Wp = WtTg + (size_t)e * 128 * KP;

    const float* srcp;
    int rbase;
    if (PREP) {
        srcp = (e == 0 ? i0 : e == 1 ? i1 : e == 2 ? i2 : i3);
        rbase = row0 - e * ROWS;
        if (TID < 64) {
            sA[TID] = rowAB[2 * (row0 + TID)];
            sB[TID] = rowAB[2 * (row0 + TID) + 1];
        }
    } else {
        srcp = U;
        rbase = row0;
    }

    int w  = TID >> 6;
    int l  = LANE;
    int wr = (w & 1) * 32;
    int wc = (w >> 1) * 64;
    int fr = l & 15;
    int koff = (l >> 4) * 8;

    f32x4 acc[2][4];
    #pragma unroll
    for (int rt = 0; rt < 2; ++rt)
        #pragma unroll
        for (int ct = 0; ct < 4; ++ct)
            acc[rt][ct] = (f32x4){0.f, 0.f, 0.f, 0.f};

    for (int k0 = 0; k0 < KP; k0 += 64) {
        __syncthreads();
        #pragma unroll
        for (int t = 0; t < 2; ++t) {
            int idx = TID + t * 256;
            int row = idx >> 3;
            int kq  = idx & 7;
            int gk  = k0 + kq * 8;
            u16x8 o;
            if (gk < K) {
                const float* sp = &srcp[(size_t)(rbase + row) * K + gk];
                float4 v0 = *(const float4*)sp;
                float4 v1 = *(const float4*)(sp + 4);
                if (PREP) {
                    float a = sA[row], bb = sB[row];
                    v0.x = v0.x * a + bb; v0.y = v0.y * a + bb;
                    v0.z = v0.z * a + bb; v0.w = v0.w * a + bb;
                    v1.x = v1.x * a + bb; v1.y = v1.y * a + bb;
                    v1.z = v1.z * a + bb; v1.w = v1.w * a + bb;
                    if (gk == 0) v0.x = 0.f;
                }
                o[0] = f2bf(v0.x); o[1] = f2bf(v0.y); o[2] = f2bf(v0.z); o[3] = f2bf(v0.w);
                o[4] = f2bf(v1.x); o[5] = f2bf(v1.y); o[6] = f2bf(v1.z); o[7] = f2bf(v1.w);
            } else {
                o = (u16x8){0,0,0,0,0,0,0,0};
            }
            *(u16x8*)&UtL[row][kq * 8] = o;
        }
        #pragma unroll
        for (int t = 0; t < 4; ++t) {
            int idx = TID + t * 256;
            int c  = idx >> 3;
            int kq = idx & 7;
            u16x8 wv = *(const u16x8*)&Wp[(size_t)c * KP + k0 + kq * 8];
            *(u16x8*)&WtL[c][kq * 8] = wv;
        }
        __syncthreads();

        #pragma unroll
        for (int ks = 0; ks < 2; ++ks) {
            bf16x8 af[2];
            #pragma unroll
            for (int rt = 0; rt < 2; ++rt)
                af[rt] = *(const bf16x8*)&UtL[wr + rt * 16 + fr][ks * 32 + koff];
            #pragma unroll
            for (int ct = 0; ct < 4; ++ct) {
                bf16x8 bf = *(const bf16x8*)&WtL[wc + ct * 16 + fr][ks * 32 + koff];
                acc[0][ct] = __builtin_amdgcn_mfma_f32_16x16x32_bf16(af[0], bf, acc[0][ct], 0, 0, 0);
                acc[1][ct] = __builtin_amdgcn_mfma_f32_16x16x32_bf16(af[1], bf, acc[1][ct], 0, 0, 0);
            }
        }
    }

    int rq = (l >> 4) * 4;
    #pragma unroll
    for (int rt = 0; rt < 2; ++rt) {
        #pragma unroll
        for (int ct = 0; ct < 4; ++ct) {
            int col = wc + ct * 16 + fr;
            float bv = bg[e * 128 + col];
            #pragma unroll
            for (int j = 0; j < 4; ++j) {
                int row = row0 + wr + rt * 16 + rq + j;
                Y[(size_t)row * 128 + col] = acc[rt][ct][j] + bv;
            }
        }
    }
}

// =======================================================================
// inter-GEMM row chain (R14-proven)
// =======================================================================
__global__ __launch_bounds__(256) void k_mid(float* __restrict__ Y) {
    int row = blockIdx.x * 4 + (TID >> 6);
    size_t base = (size_t)row * 128;
    float v[2] = { Y[base + LANE], Y[base + 64 + LANE] };
    float ss2 = w_exp0<2>(v);
    w_log0k<2>(v, ss2);
    ss2 = w_exp0<2>(v);
    w_log0k<2>(v, ss2);
    Y[base + LANE] = v[0]; Y[base + 64 + LANE] = v[1];
}

// =======================================================================
// frechet mean; FE=true fuses the final per-row exp0 (R14-proven)
// =======================================================================
template<int NPTS, bool FE>
__global__ __launch_bounds__(256) void k_frechet_w(
    const float* __restrict__ src, size_t blk_stride, size_t p_stride,
    float* __restrict__ dst)
{
    int prob = blockIdx.x * 4 + (TID >> 6);
    const float* base = src + (size_t)prob * blk_stride;
    float pa[NPTS], pb[NPTS];
    #pragma unroll
    for (int p = 0; p < NPTS; ++p) {
        pa[p] = base[(size_t)p * p_stride + LANE];
        pb[p] = base[(size_t)p * p_stride + 64 + LANE];
    }

    if (FE) {
        float q[NPTS];
        #pragma unroll
        for (int p = 0; p < NPTS; ++p)
            q[p] = ((LANE == 0) ? 0.f : pa[p] * pa[p]) + pb[p] * pb[p];
        #pragma unroll
        for (int off = 32; off; off >>= 1) {
            #pragma unroll
            for (int p = 0; p < NPTS; ++p) q[p] += __shfl_xor(q[p], off, 64);
        }
        float ssp = 0.f;
        #pragma unroll
        for (int p = 0; p < NPTS; ++p) if (LANE == p) ssp = q[p];
        float nn  = sqrtf(fmaxf(ssp, 1e-12f));
        float th  = fminf(nn, 10.0f);
        float scp = sinhf(th) / nn;
        float c0p = sqrtf(1.0f + scp * scp * ssp);
        #pragma unroll
        for (int p = 0; p < NPTS; ++p) {
            float sc = rdlane(scp, p);
            float c0 = rdlane(c0p, p);
            pa[p] = (LANE == 0) ? c0 : pa[p] * sc;
            pb[p] *= sc;
        }
    }

    float xp = 1.0f;
    #pragma unroll
    for (int p = 0; p < NPTS; ++p) {
        float x0 = __shfl(pa[p], 0, 64);
        if (LANE == p) xp = x0;
    }
    {
        float bcl = fmaxf(xp, 1.0f + 1e-7f);
        float sq  = sqrtf(fmaxf(bcl * bcl - 1.0f, 1e-12f));
        float dd  = acoshf(bcl);
        xp = dd / sq;
    }
    float ma = 0.f, mb = 0.f;
    #pragma unroll
    for (int p = 0; p < NPTS; ++p) {
        float cp = rdlane(xp, p);
        ma = fmaf(pa[p], cp, ma);
        mb = fmaf(pb[p], cp, mb);
    }
    if (LANE == 0) ma = 0.f;
    ma *= (1.0f / NPTS); mb *= (1.0f / NPTS);
    float cur[2] = { ma, mb };
    w_exp0<2>(cur);
    float ca = cur[0], cb = cur[1];

    for (int it = 0; it < 10; ++it) {
        float part[NPTS];
        #pragma unroll
        for (int p = 0; p < NPTS; ++p)
            part[p] = fmaf(cb, pb[p], (LANE == 0) ? -ca * pa[p] : ca * pa[p]);
        #pragma unroll
        for (int off = 32; off; off >>= 1) {
            #pragma unroll
            for (int p = 0; p < NPTS; ++p) part[p] += __shfl_xor(part[p], off, 64);
        }
        float lp = 0.f;
        #pragma unroll
        for (int p = 0; p < NPTS; ++p) if (LANE == p) lp = part[p];
        float bb  = fmaxf(-lp, 1.0f + 1e-7f);
        float squ = sqrtf(fmaxf(bb * bb - 1.0f, 1e-12f));
        float ccv = acoshf(bb) / squ;
        float gg  = (LANE < NPTS) ? ccv * bb : 0.f;
        float gv  = wsum1(gg);
        float va = 0.f, vb = 0.f;
        #pragma unroll
        for (int p = 0; p < NPTS; ++p) {
            float cp = rdlane(ccv, p);
            va = fmaf(pa[p], cp, va);
            vb = fmaf(pb[p], cp, vb);
        }
        const float sscale = 0.5f / NPTS;
        va = (va - gv * ca) * sscale;
        vb = (vb - gv * cb) * sscale;
        float lin = wsum1(((LANE == 0) ? -va * va : va * va) + vb * vb);
        float n   = sqrtf(fmaxf(lin, 1e-12f));
        float th  = fminf(n, 10.0f);
        float ch  = coshf(th), shn = sinhf(th) / n;
        float ya = ch * ca + shn * va;
        float yb = ch * cb + shn * vb;
        float ss2 = wsum1(((LANE == 0) ? 0.f : ya * ya) + yb * yb);
        ca = (LANE == 0) ? sqrtf(1.0f + ss2) : ya;
        cb = yb;
    }
    dst[(size_t)prob * 128 + LANE] = ca;
    dst[(size_t)prob * 128 + 64 + LANE] = cb;
}

// =======================================================================
// fused decode v4 (R14-proven verbatim)
// =======================================================================
__global__ __launch_bounds__(512) void k_decode_all(
    const float* __restrict__ comb,
    const float* __restrict__ dW0, const float* __restrict__ db0,
    const float* __restrict__ dW1, const float* __restrict__ db1,
    const float* __restrict__ dW2, const float* __restrict__ db2,
    const float* __restrict__ step_p, const float* __restrict__ alpha_p,
    const float* __restrict__ cW0, const float* __restrict__ cb0,
    const float* __restrict__ lng, const float* __restrict__ lnb,
    const float* __restrict__ cW1, const float* __restrict__ cb1,
    float* __restrict__ out)
{
    __shared__ float uT[2][256];
    __shared__ float Bbuf[2][256];
    __shared__ float part[1024];
    int w = TID >> 6;
    int row0 = blockIdx.x * 2;

    float zc0 = 1.f, zc1 = 0.f, x0 = 1.f, x1 = 0.f;
    if (w < 2) {
        size_t rb = (size_t)(row0 + w) * ED;
        zc0 = comb[rb + LANE]; zc1 = comb[rb + 64 + LANE];
        x0 = zc0; x1 = zc1;
    }
    float stp = 1.0f / (1.0f + expf(-step_p[0]));
    float aa  = 1.0f / (1.0f + expf(-alpha_p[0]));

    for (int s = 0; s < 4; ++s) {
        // ---- phase 1 (waves 0-1)
        if (w < 2) {
            float xx[2] = { x0, x1 };
            float zz[2] = { zc0, zc1 };
            float lin  = wlinE<2>(xx, zz);
            float beta = fmaxf(-lin, 1.0f + 1e-7f);
            float un   = sqrtf(fmaxf(beta * beta - 1.0f, 1e-12f));
            float sc   = acoshf(beta) / un;
            float v[2] = { sc * (zz[0] - beta * xx[0]), sc * (zz[1] - beta * xx[1]) };
            float ss2 = w_exp0<2>(v);
            w_log0k<2>(v, ss2);
            uT[w][LANE] = v[0]; uT[w][64 + LANE] = v[1];
        }
        __syncthreads();

        // ---- phase 2: y1 = u1 @ dW0 + db0  (128 -> 256), K-split 2
        {
            int kh = TID >> 8;
            int col = TID & 255;
            int k0 = kh * 64;
            float a0 = 0.f, a1 = 0.f;
            #pragma unroll 8
            for (int i = 0; i < 64; ++i) {
                float u0 = uT[0][k0 + i], u1 = uT[1][k0 + i];
                float wv = dW0[(size_t)(k0 + i) * HD + col];
                a0 = fmaf(u0, wv, a0); a1 = fmaf(u1, wv, a1);
            }
            if (kh == 1) { part[col] = a0; part[256 + col] = a1; }
            __syncthreads();
            if (kh == 0) {
                float b = db0[col];
                Bbuf[0][col] = a0 + part[col] + b;
                Bbuf[1][col] = a1 + part[256 + col] + b;
            }
        }
        __syncthreads();

        // ---- phase 3 (waves 0-1): u2 = mid-chain(y1)
        if (w < 2) {
            float y[4];
            #pragma unroll
            for (int t = 0; t < 4; ++t) y[t] = Bbuf[w][t * 64 + LANE];
            float ss2 = w_exp0<4>(y);
            w_log0k<4>(y, ss2);
            ss2 = w_exp0<4>(y);
            w_log0k<4>(y, ss2);
            #pragma unroll
            for (int t = 0; t < 4; ++t) uT[w][t * 64 + LANE] = y[t];
        }
        __syncthreads();

        // ---- phase 4: y2 = u2 @ dW1 + db1  (256 -> 256), K-split 2
        {
            int kh = TID >> 8;
            int col = TID & 255;
            int k0 = kh * 128;
            float a0 = 0.f, a1 = 0.f;
            #pragma unroll 8
            for (int i = 0; i < 128; ++i) {
                float u0 = uT[0][k0 + i], u1 = uT[1][k0 + i];
                float wv = dW1[(size_t)(k0 + i) * HD + col];
                a0 = fmaf(u0, wv, a0); a1 = fmaf(u1, wv, a1);
            }
            if (kh == 1) { part[col] = a0; part[256 + col] = a1; }
            __syncthreads();
            if (kh == 0) {
                float b = db1[col];
                Bbuf[0][col] = a0 + part[col] + b;
                Bbuf[1][col] = a1 + part[256 + col] + b;
            }
        }
        __syncthreads();

        // ---- phase 5 (waves 0-1): u3 = mid-chain(y2)
        if (w < 2) {
            float y[4];
            #pragma unroll
            for (int t = 0; t < 4; ++t) y[t] = Bbuf[w][t * 64 + LANE];
            float ss2 = w_exp0<4>(y);
            w_log0k<4>(y, ss2);
            ss2 = w_exp0<4>(y);
            w_log0k<4>(y, ss2);
            #pragma unroll
            for (int t = 0; t < 4; ++t) uT[w][t * 64 + LANE] = y[t];
        }
        __syncthreads();

        // ---- phase 6: y3 = u3 @ dW2 + db2  (256 -> 128), K-split 4
        {
            int kq = TID >> 7;
            int col = TID & 127;
            int k0 = kq * 64;
            float a0 = 0.f, a1 = 0.f;
            #pragma unroll 8
            for (int i = 0; i < 64; ++i) {
                float u0 = uT[0][k0 + i], u1 = uT[1][k0 + i];
                float wv = dW2[(size_t)(k0 + i) * ED + col];
                a0 = fmaf(u0, wv, a0); a1 = fmaf(u1, wv, a1);
            }
            if (kq > 0) {
                part[(kq - 1) * 256 + col] = a0;
                part[(kq - 1) * 256 + 128 + col] = a1;
            }
            __syncthreads();
            if (kq == 0) {
                float b = db2[col];
                float s0 = a0, s1 = a1;
                #pragma unroll
                for (int q = 0; q < 3; ++q) {
                    s0 += part[q * 256 + col];
                    s1 += part[q * 256 + 128 + col];
                }
                Bbuf[0][col] = s0 + b;
                Bbuf[1][col] = s1 + b;
            }
        }
        __syncthreads();

        // ---- phase 7 (waves 0-1): vtr; zstep; rotate; u4
        if (w < 2) {
            float y[2] = { Bbuf[w][LANE], Bbuf[w][64 + LANE] };
            float ss2v = w_exp0<2>(y);
            w_log0k<2>(y, ss2v);

            float z[2] = { zc0, zc1 };
            float u[2] = { stp * y[0], stp * y[1] };
            float lin1 = wlinE<2>(u, u);
            float n1   = sqrtf(fmaxf(lin1, 1e-12f));
            float th1  = fminf(n1, 10.0f);
            float ch1  = coshf(th1), sh1 = sinhf(th1) / n1;
            float zu[2] = { ch1 * z[0] + sh1 * u[0], ch1 * z[1] + sh1 * u[1] };
            float s2 = wsum1(((LANE == 0) ? 0.f : zu[0] * zu[0]) + zu[1] * zu[1]);
            if (LANE == 0) zu[0] = sqrtf(1.0f + s2);
            float lin2 = wlinE<2>(z, zu);
            float beta = fmaxf(-lin2, 1.0f + 1e-7f);
            float un   = sqrtf(fmaxf(beta * beta - 1.0f, 1e-12f));
            float dd   = acoshf(beta);
            float sc   = dd / un;
            float g0 = (1.0f - aa) * sc * (zu[0] - beta * z[0]);
            float g1 = (1.0f - aa) * sc * (zu[1] - beta * z[1]);
            float n3  = sqrtf(fmaxf((1.0f - aa) * (1.0f - aa) * dd * dd, 1e-12f));
            float th3 = fminf(n3, 10.0f);
            float ch3 = coshf(th3), sh3 = sinhf(th3) / n3;
            float y0 = ch3 * z[0] + sh3 * g0;
            float y1 = ch3 * z[1] + sh3 * g1;
            float s3 = wsum1(((LANE == 0) ? 0.f : y0 * y0) + y1 * y1);
            if (LANE == 0) y0 = sqrtf(1.0f + s3);
            x0 = zc0; x1 = zc1;
            zc0 = y0; zc1 = y1;
            float x0b = sqrtf(1.0f + s3);
            float dd2 = acoshf(fmaxf(x0b, 1.0f + 1e-7f));
            float sc4 = dd2 / sqrtf(fmaxf(s3, 1e-12f));
            uT[w][LANE]      = (LANE == 0) ? 0.f : y0 * sc4;
            uT[w][64 + LANE] = y1 * sc4;
        }
        __syncthreads();

        // ---- phase 8: t = u4 @ cW0 + cb0  (128 -> 256), K-split 2
        {
            int kh = TID >> 8;
            int col = TID & 255;
            int k0 = kh * 64;
            float a0 = 0.f, a1 = 0.f;
            #pragma unroll 8
            for (int i = 0; i < 64; ++i) {
                float u0 = uT[0][k0 + i], u1 = uT[1][k0 + i];
                float wv = cW0[(size_t)(k0 + i) * HD + col];
                a0 = fmaf(u0, wv, a0); a1 = fmaf(u1, wv, a1);
            }
            if (kh == 1) { part[col] = a0; part[256 + col] = a1; }
            __syncthreads();
            if (kh == 0) {
                float b = cb0[col];
                Bbuf[0][col] = a0 + part[col] + b;
                Bbuf[1][col] = a1 + part[256 + col] + b;
            }
        }
        __syncthreads();

        // ---- phase 9 (waves 0-1): LayerNorm + exact GELU
        if (w < 2) {
            float tv[4];
            #pragma unroll
            for (int t = 0; t < 4; ++t) tv[t] = Bbuf[w][t * 64 + LANE];
            float m = wsum1(tv[0] + tv[1] + tv[2] + tv[3]) * (1.0f / 256.0f);
            float c[4]; float vs = 0.f;
            #pragma unroll
            for (int t = 0; t < 4; ++t) { c[t] = tv[t] - m; vs += c[t] * c[t]; }
            float var = wsum1(vs) * (1.0f / 256.0f);
            float rstd = 1.0f / sqrtf(var + 1e-5f);
            #pragma unroll
            for (int t = 0; t < 4; ++t) {
                float g = lng[t * 64 + LANE], bb = lnb[t * 64 + LANE];
                float x = c[t] * rstd * g + bb;
                uT[w][t * 64 + LANE] = 0.5f * x * (1.0f + erff(x * 0.70710678118654752f));
            }
        }
        __syncthreads();

        // ---- phase 10: out = gelu(t) @ cW1 + cb1  (256 -> 504), K-split 2
        {
            int kh = TID >> 8;
            int c  = TID & 255;
            bool hi = (c < 248);
            int k0 = kh * 128;
            float a00 = 0.f, a01 = 0.f, a10 = 0.f, a11 = 0.f;
            #pragma unroll 8
            for (int i = 0; i < 128; ++i) {
                float u0 = uT[0][k0 + i], u1 = uT[1][k0 + i];
                float wA = cW1[(size_t)(k0 + i) * 504 + c];
                float wB = hi ? cW1[(size_t)(k0 + i) * 504 + c + 256] : 0.f;
                a00 = fmaf(u0, wA, a00); a01 = fmaf(u0, wB, a01);
                a10 = fmaf(u1, wA, a10); a11 = fmaf(u1, wB, a11);
            }
            if (kh == 1) {
                part[c] = a00; part[256 + c] = a01;
                part[512 + c] = a10; part[768 + c] = a11;
            }
            __syncthreads();
            if (kh == 0) {
                float bA = cb1[c];
                float bB = hi ? cb1[c + 256] : 0.f;
                size_t ob0 = (size_t)(row0 + 0) * 2016 + (size_t)s * 504;
                size_t ob1 = (size_t)(row0 + 1) * 2016 + (size_t)s * 504;
                out[ob0 + c] = a00 + part[c] + bA;
                out[ob1 + c] = a10 + part[512 + c] + bA;
                if (hi) {
                    out[ob0 + c + 256] = a01 + part[256 + c] + bB;
                    out[ob1 + c + 256] = a11 + part[768 + c] + bB;
                }
            }
        }
        __syncthreads();
    }
}

// ---------- launch ----------
extern "C" void kernel_launch(void* const* d_in, const int* in_sizes, int n_in,
                              void* d_out, int out_size, void* d_ws, size_t ws_size,
                              hipStream_t stream) {
    const float* trend = (const float*)d_in[0];
    const float* scrs  = (const float*)d_in[1];
    const float* sfin  = (const float*)d_in[2];
    const float* resid = (const float*)d_in[3];
    const float* eW0 = (const float*)d_in[4];
    const float* eb0 = (const float*)d_in[5];
    const float* eW1 = (const float*)d_in[6];
    const float* eb1 = (const float*)d_in[7];
    const float* eW2 = (const float*)d_in[8];
    const float* eb2 = (const float*)d_in[9];
    const float* esc = (const float*)d_in[10];
    const float* dW0 = (const float*)d_in[12];
    const float* db0 = (const float*)d_in[13];
    const float* dW1 = (const float*)d_in[14];
    const float* db1 = (const float*)d_in[15];
    const float* dW2 = (const float*)d_in[16];
    const float* db2 = (const float*)d_in[17];
    const float* alpha_p = (const float*)d_in[18];
    const float* step_p  = (const float*)d_in[19];
    const float* cW0 = (const float*)d_in[20];
    const float* cb0 = (const float*)d_in[21];
    const float* lng = (const float*)d_in[22];
    const float* lnb = (const float*)d_in[23];
    const float* cW1 = (const float*)d_in[24];
    const float* cb1 = (const float*)d_in[25];
    float* outp = (float*)d_out;

    float* w = (float*)d_ws;
    float* Y      = w;                        // 7,340,032 f32
    float* pooled = Y + 7340032;              // 524,288
    float* comb   = pooled + 524288;          // 131,072
    float* rowAB  = comb + 131072;            // 114,688
    unsigned short* WtT0 = (unsigned short*)(rowAB + 114688);  // 4*128*512 u16
    unsigned short* WtT1 = WtT0 + 4 * 128 * 512;               // 4*128*128 u16
    unsigned short* WtT2 = WtT1 + 4 * 128 * 128;               // 4*128*128 u16

    // ---- weight pre-transpose + bf16 convert ----
    k_wtrans<504, 512><<<(4 * 128 * 512) / 256, 256, 0, stream>>>(eW0, WtT0);
    k_wtrans2<<<(2 * 4 * 128 * 128) / 256, 256, 0, stream>>>(eW1, WtT1, eW2, WtT2);

    // ---- encoder: bf16 MFMA GEMMs + row chains ----
    k_prep_stats<<<NROWS / 4, 256, 0, stream>>>(trend, scrs, sfin, resid, esc, rowAB);
    k_gemm_bf<504, 512, true><<<NROWS / 64, 256, 0, stream>>>(
        nullptr, trend, scrs, sfin, resid, rowAB, WtT0, eb0, Y);
    k_mid<<<NROWS / 4, 256, 0, stream>>>(Y);
    k_gemm_bf<128, 128, false><<<NROWS / 64, 256, 0, stream>>>(
        Y, nullptr, nullptr, nullptr, nullptr, nullptr, WtT1, eb1, Y);
    k_mid<<<NROWS / 4, 256, 0, stream>>>(Y);
    k_gemm_bf<128, 128, false><<<NROWS / 64, 256, 0, stream>>>(
        Y, nullptr, nullptr, nullptr, nullptr, nullptr, WtT2, eb2, Y);
    // k_post fused into k_frechet_w<NSEG, true>

    // ---- frechet pooling (point-load applies exp0 = old k_post) ----
    k_frechet_w<NSEG, true><<<(4 * NB) / 4, 256, 0, stream>>>(
        Y, (size_t)NSEG * ED, (size_t)ED, pooled);
    k_frechet_w<4, false><<<NB / 4, 256, 0, stream>>>(
        pooled, (size_t)ED, (size_t)NB * ED, comb);

    // ---- decode (R14-proven) ----
    k_decode_all<<<NB / 2, 512, 0, stream>>>(
        comb, dW0, db0, dW1, db1, dW2, db2, step_p, alpha_p,
        cW0, cb0, lng, lnb, cW1, cb1, outp);
}